// Round 13
// baseline (203.798 us; speedup 1.0000x reference)
//
#include <hip/hip_runtime.h>
#include <math.h>

#define M_OBJ 4
#define N_PTS 3072
#define K_NN  10
#define NSLOT (M_OBJ - 1)
#define QSL   3                   // query slots per lane (hand-named)
#define QPB   (64 * QSL)          // 192 queries per block
#define NQCH  (N_PTS / QPB)       // 16 query chunks
#define HSPLIT 4
#define HPTS  (N_PTS / HSPLIT)    // 768 ref points per block
#define SEGN  (HPTS / 4)          // 192 points per wave segment
#define NCHUNK (SEGN / 64)        // 3
#define NWARM (SEGN / 16)         // 12 warm points, stride 16
#define IDMASK 0xFFFu             // 12-bit global point id
#define PKMASK 0x1FFFu            // 12 id bits + 1 vote bit cleared at pack

// T = inv(plane_T) @ est_T (3x4). plane_T orthonormal-rigid: inv = [R^T|-R^T t].
__device__ inline void make_T(const float* __restrict__ E,
                              const float* __restrict__ P,
                              float T[3][4]) {
    float Pi[3][4];
#pragma unroll
    for (int i = 0; i < 3; ++i) {
#pragma unroll
        for (int j = 0; j < 3; ++j) Pi[i][j] = P[j * 4 + i];
        Pi[i][3] = -(P[0 * 4 + i] * P[3] + P[1 * 4 + i] * P[7] + P[2 * 4 + i] * P[11]);
    }
#pragma unroll
    for (int i = 0; i < 3; ++i) {
#pragma unroll
        for (int j = 0; j < 4; ++j) {
            float acc = (j == 3) ? Pi[i][3] : 0.0f;
#pragma unroll
            for (int kk = 0; kk < 3; ++kk) acc += Pi[i][kk] * E[kk * 4 + j];
            T[i][j] = acc;
        }
    }
}

// ascending insert-drop-min via med3 identity; no-op when v <= bs[0]
__device__ __forceinline__ void insertv(float v, float bs[K_NN]) {
#pragma unroll
    for (int i = 0; i < K_NN - 1; ++i)
        bs[i] = __builtin_amdgcn_fmed3f(v, bs[i], bs[i + 1]);
    bs[K_NN - 1] = fmaxf(v, bs[K_NN - 1]);
}

__device__ __forceinline__ float score4(const float4 p, float qx, float qy, float qz) {
    return fmaf(p.x, qx, fmaf(p.y, qy, fmaf(p.z, qz, -p.w)));
}

// pack score with GLOBAL id in low 12 bits; bit 12 reserved (cleared) for vote
#define PACKG(P, GID, QX, QY, QZ) \
    __uint_as_float((__float_as_uint(score4((P), (QX), (QY), (QZ))) & ~PKMASK) | (unsigned)(GID))
// fallback pack (12-bit clear, id only)
#define PACKQ(P, LID, QX, QY, QZ) \
    __uint_as_float((__float_as_uint(score4((P), (QX), (QY), (QZ))) & ~IDMASK) | (unsigned)(LID))

#define GATE_OF(B0) (fmaf(-fabsf(B0), 1.0e-3f, (B0)) - 1e-30f)

// ---------------- main path: 768 uniform blocks (3/CU), Q=3, H=4 ----------
// launch_bounds min-waves = 1: state needs ~240 VGPR; declaring 2 caps at 128
// and spills 625 MB/dispatch (measured round 11). 2 waves/SIMD co-resident.
__global__ __launch_bounds__(256, 1) void pair_part_kernel(
        const float* __restrict__ points,   // [M][N][6]
        const float* __restrict__ estT,     // [M][4][4]
        const float* __restrict__ planeT,   // [4][4]
        float* __restrict__ part) {         // [12][H][10][N] packed
    __shared__ float4 sref[HPTS];               // 12288 B
    __shared__ float  mbuf[128 * QSL * K_NN];   // 15360 B

    const int pidx  = blockIdx.x;           // 0..11
    const int qc    = blockIdx.y;           // 0..15
    const int h     = blockIdx.z;           // 0..3
    const int hbase = h * HPTS;
    const int q     = pidx / NSLOT;
    const int rs    = pidx % NSLOT;
    const int r     = rs + (rs >= q ? 1 : 0);
    const int tid   = threadIdx.x;
    const int seg   = tid >> 6;
    const int qlane = tid & 63;

    float Tq[3][4], Tr[3][4];
    make_T(estT + q * 16, planeT, Tq);
    make_T(estT + r * 16, planeT, Tr);

    for (int j = tid; j < HPTS; j += 256) {
        const float* p = points + (size_t)(r * N_PTS + hbase + j) * 6;
        float2 xy = *(const float2*)p;
        float  z  = p[2];
        float px = Tr[0][0] * xy.x + Tr[0][1] * xy.y + Tr[0][2] * z + Tr[0][3];
        float py = Tr[1][0] * xy.x + Tr[1][1] * xy.y + Tr[1][2] * z + Tr[1][3];
        float pz = Tr[2][0] * xy.x + Tr[2][1] * xy.y + Tr[2][2] * z + Tr[2][3];
        sref[j] = make_float4(px, py, pz, 0.5f * (px * px + py * py + pz * pz));
    }
    __syncthreads();

    const int nqA = qc * QPB + 0 * 64 + qlane;
    const int nqB = qc * QPB + 1 * 64 + qlane;
    const int nqC = qc * QPB + 2 * 64 + qlane;
    const float* qpA = points + (size_t)(q * N_PTS + nqA) * 6;
    const float* qpB = points + (size_t)(q * N_PTS + nqB) * 6;
    const float* qpC = points + (size_t)(q * N_PTS + nqC) * 6;
    float2 axy = *(const float2*)qpA; float az = qpA[2];
    float2 bxy = *(const float2*)qpB; float bz = qpB[2];
    float2 cxy = *(const float2*)qpC; float cz = qpC[2];
    const float qxA = Tq[0][0]*axy.x + Tq[0][1]*axy.y + Tq[0][2]*az + Tq[0][3];
    const float qyA = Tq[1][0]*axy.x + Tq[1][1]*axy.y + Tq[1][2]*az + Tq[1][3];
    const float qzA = Tq[2][0]*axy.x + Tq[2][1]*axy.y + Tq[2][2]*az + Tq[2][3];
    const float qxB = Tq[0][0]*bxy.x + Tq[0][1]*bxy.y + Tq[0][2]*bz + Tq[0][3];
    const float qyB = Tq[1][0]*bxy.x + Tq[1][1]*bxy.y + Tq[1][2]*bz + Tq[1][3];
    const float qzB = Tq[2][0]*bxy.x + Tq[2][1]*bxy.y + Tq[2][2]*bz + Tq[2][3];
    const float qxC = Tq[0][0]*cxy.x + Tq[0][1]*cxy.y + Tq[0][2]*cz + Tq[0][3];
    const float qyC = Tq[1][0]*cxy.x + Tq[1][1]*cxy.y + Tq[1][2]*cz + Tq[1][3];
    const float qzC = Tq[2][0]*cxy.x + Tq[2][1]*cxy.y + Tq[2][2]*cz + Tq[2][3];

    float bsA[K_NN], bsB[K_NN], bsC[K_NN];
#pragma unroll
    for (int i = 0; i < K_NN; ++i) { bsA[i] = -3.4e38f; bsB[i] = -3.4e38f; bsC[i] = -3.4e38f; }

    const int j0 = seg * SEGN;

    for (int k = 0; k < NWARM; ++k) {
        const int lid = j0 + k * 16;
        const float4 p = sref[lid];
        insertv(PACKG(p, hbase + lid, qxA, qyA, qzA), bsA);
        insertv(PACKG(p, hbase + lid, qxB, qyB, qzB), bsB);
        insertv(PACKG(p, hbase + lid, qxC, qyC, qzC), bsC);
    }

    for (int c = 0; c < NCHUNK; ++c) {
        const int jj = j0 + c * 64;
        const float gA = GATE_OF(bsA[0]);
        const float gB = GATE_OF(bsB[0]);
        const float gC = GATE_OF(bsC[0]);
        unsigned mA0 = 0u, mA1 = 0u, mB0 = 0u, mB1 = 0u, mC0 = 0u, mC1 = 0u;
#pragma unroll
        for (int b = 0; b < 32; ++b) {
            const float4 p = sref[jj + b];
            mA0 |= (score4(p, qxA, qyA, qzA) > gA) ? (1u << b) : 0u;
            mB0 |= (score4(p, qxB, qyB, qzB) > gB) ? (1u << b) : 0u;
            mC0 |= (score4(p, qxC, qyC, qzC) > gC) ? (1u << b) : 0u;
        }
#pragma unroll
        for (int b = 0; b < 32; ++b) {
            const float4 p = sref[jj + 32 + b];
            mA1 |= (score4(p, qxA, qyA, qzA) > gA) ? (1u << b) : 0u;
            mB1 |= (score4(p, qxB, qyB, qzB) > gB) ? (1u << b) : 0u;
            mC1 |= (score4(p, qxC, qyC, qzC) > gC) ? (1u << b) : 0u;
        }
        mA0 &= ~0x00010001u; mA1 &= ~0x00010001u;   // warm points already in
        mB0 &= ~0x00010001u; mB1 &= ~0x00010001u;
        mC0 &= ~0x00010001u; mC1 &= ~0x00010001u;

        while (__any((mA0 | mA1) != 0u)) {
            if (mA0) { const int b = __builtin_ctz(mA0); mA0 &= mA0 - 1u;
                const int lid = jj + b;      insertv(PACKG(sref[lid], hbase + lid, qxA, qyA, qzA), bsA); }
            if (mA1) { const int b = __builtin_ctz(mA1); mA1 &= mA1 - 1u;
                const int lid = jj + 32 + b; insertv(PACKG(sref[lid], hbase + lid, qxA, qyA, qzA), bsA); }
        }
        while (__any((mB0 | mB1) != 0u)) {
            if (mB0) { const int b = __builtin_ctz(mB0); mB0 &= mB0 - 1u;
                const int lid = jj + b;      insertv(PACKG(sref[lid], hbase + lid, qxB, qyB, qzB), bsB); }
            if (mB1) { const int b = __builtin_ctz(mB1); mB1 &= mB1 - 1u;
                const int lid = jj + 32 + b; insertv(PACKG(sref[lid], hbase + lid, qxB, qyB, qzB), bsB); }
        }
        while (__any((mC0 | mC1) != 0u)) {
            if (mC0) { const int b = __builtin_ctz(mC0); mC0 &= mC0 - 1u;
                const int lid = jj + b;      insertv(PACKG(sref[lid], hbase + lid, qxC, qyC, qzC), bsC); }
            if (mC1) { const int b = __builtin_ctz(mC1); mC1 &= mC1 - 1u;
                const int lid = jj + 32 + b; insertv(PACKG(sref[lid], hbase + lid, qxC, qyC, qzC), bsC); }
        }
    }

    // cascade merge across the 4 wave segments
    __syncthreads();
    if (seg >= 2) {
        const int slot = tid - 128;
#pragma unroll
        for (int i = 0; i < K_NN; ++i) {
            mbuf[(slot * QSL + 0) * K_NN + i] = bsA[i];
            mbuf[(slot * QSL + 1) * K_NN + i] = bsB[i];
            mbuf[(slot * QSL + 2) * K_NN + i] = bsC[i];
        }
    }
    __syncthreads();
    if (seg < 2) {
        const int src = seg * 64 + qlane;
#pragma unroll
        for (int i = 0; i < K_NN; ++i) {
            insertv(mbuf[(src * QSL + 0) * K_NN + i], bsA);
            insertv(mbuf[(src * QSL + 1) * K_NN + i], bsB);
            insertv(mbuf[(src * QSL + 2) * K_NN + i], bsC);
        }
    }
    __syncthreads();
    if (seg == 1) {
#pragma unroll
        for (int i = 0; i < K_NN; ++i) {
            mbuf[(qlane * QSL + 0) * K_NN + i] = bsA[i];
            mbuf[(qlane * QSL + 1) * K_NN + i] = bsB[i];
            mbuf[(qlane * QSL + 2) * K_NN + i] = bsC[i];
        }
    }
    __syncthreads();
    if (seg == 0) {
#pragma unroll
        for (int i = 0; i < K_NN; ++i) {
            insertv(mbuf[(qlane * QSL + 0) * K_NN + i], bsA);
            insertv(mbuf[(qlane * QSL + 1) * K_NN + i], bsB);
            insertv(mbuf[(qlane * QSL + 2) * K_NN + i], bsC);
        }

        const float* nrm_base = points + (size_t)r * N_PTS * 6 + 3;
        const size_t pb = (size_t)(pidx * HSPLIT + h) * K_NN;

        // vote at result frequency; OR into bit 12; write coalesced partials
        {
#pragma unroll
            for (int i = 0; i < K_NN; ++i) {
                unsigned bits = __float_as_uint(bsA[i]);
                const int gid = (int)(bits & IDMASK);
                const float4 p = sref[gid - hbase];
                const float* nb = nrm_base + (size_t)gid * 6;
                float dv = fmaf(nb[0], p.x-qxA, fmaf(nb[1], p.y-qyA, nb[2]*(p.z-qzA)));
                bits |= (dv > 0.0f) ? (1u << 12) : 0u;
                part[(pb + i) * N_PTS + nqA] = __uint_as_float(bits);
            }
        }
        {
#pragma unroll
            for (int i = 0; i < K_NN; ++i) {
                unsigned bits = __float_as_uint(bsB[i]);
                const int gid = (int)(bits & IDMASK);
                const float4 p = sref[gid - hbase];
                const float* nb = nrm_base + (size_t)gid * 6;
                float dv = fmaf(nb[0], p.x-qxB, fmaf(nb[1], p.y-qyB, nb[2]*(p.z-qzB)));
                bits |= (dv > 0.0f) ? (1u << 12) : 0u;
                part[(pb + i) * N_PTS + nqB] = __uint_as_float(bits);
            }
        }
        {
#pragma unroll
            for (int i = 0; i < K_NN; ++i) {
                unsigned bits = __float_as_uint(bsC[i]);
                const int gid = (int)(bits & IDMASK);
                const float4 p = sref[gid - hbase];
                const float* nb = nrm_base + (size_t)gid * 6;
                float dv = fmaf(nb[0], p.x-qxC, fmaf(nb[1], p.y-qyC, nb[2]*(p.z-qzC)));
                bits |= (dv > 0.0f) ? (1u << 12) : 0u;
                part[(pb + i) * N_PTS + nqC] = __uint_as_float(bits);
            }
        }
    }
}

__global__ __launch_bounds__(256) void merge_kernel(
        const float* __restrict__ points,
        const float* __restrict__ estT,
        const float* __restrict__ planeT,
        const float* __restrict__ part,     // [12][H][10][N]
        float* __restrict__ out) {
    int i = blockIdx.x * blockDim.x + threadIdx.x;
    if (i >= M_OBJ * N_PTS) return;
    const int m = i / N_PTS, n = i % N_PTS;

    float Tq[3][4];
    make_T(estT + m * 16, planeT, Tq);
    const float* qp = points + (size_t)i * 6;
    const float qx = Tq[0][0]*qp[0] + Tq[0][1]*qp[1] + Tq[0][2]*qp[2] + Tq[0][3];
    const float qy = Tq[1][0]*qp[0] + Tq[1][1]*qp[1] + Tq[1][2]*qp[2] + Tq[1][3];
    const float qz = Tq[2][0]*qp[0] + Tq[2][1]*qp[1] + Tq[2][2]*qp[2] + Tq[2][3];

    float sd = qz;                           // plane distance
#pragma unroll
    for (int rs = 0; rs < NSLOT; ++rs) {
        const int r = rs + (rs >= m ? 1 : 0);
        const size_t pb = (size_t)((m * NSLOT + rs) * HSPLIT) * K_NN;
        float bs[K_NN];
#pragma unroll
        for (int k = 0; k < K_NN; ++k) bs[k] = -3.4e38f;
#pragma unroll
        for (int h = 0; h < HSPLIT; ++h)
#pragma unroll
            for (int k = 0; k < K_NN; ++k)
                insertv(part[(pb + (size_t)h * K_NN + k) * N_PTS + n], bs);

        int votes = 0;
#pragma unroll
        for (int k = 0; k < K_NN; ++k)
            votes += (int)((__float_as_uint(bs[k]) >> 12) & 1u);

        const int gid = (int)(__float_as_uint(bs[K_NN - 1]) & IDMASK);
        float Tr[3][4];
        make_T(estT + r * 16, planeT, Tr);
        const float* pp = points + (size_t)(r * N_PTS + gid) * 6;
        const float rx = Tr[0][0]*pp[0] + Tr[0][1]*pp[1] + Tr[0][2]*pp[2] + Tr[0][3];
        const float ry = Tr[1][0]*pp[0] + Tr[1][1]*pp[1] + Tr[1][2]*pp[2] + Tr[1][3];
        const float rz = Tr[2][0]*pp[0] + Tr[2][1]*pp[1] + Tr[2][2]*pp[2] + Tr[2][3];
        const float dx = rx - qx, dy = ry - qy, dz = rz - qz;
        const float d0 = sqrtf(fmaf(dx, dx, fmaf(dy, dy, dz * dz)));
        sd = fminf(sd, (votes > 8) ? -d0 : d0);
    }
    out[i] = sd;
    out[M_OBJ * N_PTS + i] = (sd < -0.01f) ? 1.0f : 0.0f;
}

// ---------------- fallback (round-12 proven, ws-guard) --------------------
#define SEGF   (N_PTS / 4)
#define NCHF   (SEGF / 64)
#define NWARMF (SEGF / 16)

__global__ __launch_bounds__(256, 1) void pair_kernel_fb(
        const float* __restrict__ points, const float* __restrict__ estT,
        const float* __restrict__ planeT, float* __restrict__ pair_sd) {
    __shared__ float4 sref[N_PTS];
    __shared__ float  mbuf[128 * QSL * K_NN];
    const int pidx = blockIdx.x, qc = blockIdx.y;
    const int q = pidx / NSLOT, rs = pidx % NSLOT;
    const int r = rs + (rs >= q ? 1 : 0);
    const int tid = threadIdx.x, seg = tid >> 6, qlane = tid & 63;
    float Tq[3][4], Tr[3][4];
    make_T(estT + q * 16, planeT, Tq);
    make_T(estT + r * 16, planeT, Tr);
    for (int j = tid; j < N_PTS; j += 256) {
        const float* p = points + (size_t)(r * N_PTS + j) * 6;
        float2 xy = *(const float2*)p; float z = p[2];
        float px = Tr[0][0]*xy.x + Tr[0][1]*xy.y + Tr[0][2]*z + Tr[0][3];
        float py = Tr[1][0]*xy.x + Tr[1][1]*xy.y + Tr[1][2]*z + Tr[1][3];
        float pz = Tr[2][0]*xy.x + Tr[2][1]*xy.y + Tr[2][2]*z + Tr[2][3];
        sref[j] = make_float4(px, py, pz, 0.5f*(px*px+py*py+pz*pz));
    }
    __syncthreads();
    const int nqA = qc * QPB + qlane, nqB = nqA + 64, nqC = nqA + 128;
    const float* qpA = points + (size_t)(q * N_PTS + nqA) * 6;
    const float* qpB = points + (size_t)(q * N_PTS + nqB) * 6;
    const float* qpC = points + (size_t)(q * N_PTS + nqC) * 6;
    float2 axy = *(const float2*)qpA; float az = qpA[2];
    float2 bxy = *(const float2*)qpB; float bz = qpB[2];
    float2 cxy = *(const float2*)qpC; float cz = qpC[2];
    const float qxA = Tq[0][0]*axy.x + Tq[0][1]*axy.y + Tq[0][2]*az + Tq[0][3];
    const float qyA = Tq[1][0]*axy.x + Tq[1][1]*axy.y + Tq[1][2]*az + Tq[1][3];
    const float qzA = Tq[2][0]*axy.x + Tq[2][1]*axy.y + Tq[2][2]*az + Tq[2][3];
    const float qxB = Tq[0][0]*bxy.x + Tq[0][1]*bxy.y + Tq[0][2]*bz + Tq[0][3];
    const float qyB = Tq[1][0]*bxy.x + Tq[1][1]*bxy.y + Tq[1][2]*bz + Tq[1][3];
    const float qzB = Tq[2][0]*bxy.x + Tq[2][1]*bxy.y + Tq[2][2]*bz + Tq[2][3];
    const float qxC = Tq[0][0]*cxy.x + Tq[0][1]*cxy.y + Tq[0][2]*cz + Tq[0][3];
    const float qyC = Tq[1][0]*cxy.x + Tq[1][1]*cxy.y + Tq[1][2]*cz + Tq[1][3];
    const float qzC = Tq[2][0]*cxy.x + Tq[2][1]*cxy.y + Tq[2][2]*cz + Tq[2][3];
    const float qqA = qxA*qxA + qyA*qyA + qzA*qzA;
    const float qqB = qxB*qxB + qyB*qyB + qzB*qzB;
    const float qqC = qxC*qxC + qyC*qyC + qzC*qzC;
    float bsA[K_NN], bsB[K_NN], bsC[K_NN];
#pragma unroll
    for (int i = 0; i < K_NN; ++i) { bsA[i] = -3.4e38f; bsB[i] = -3.4e38f; bsC[i] = -3.4e38f; }
    const int j0 = seg * SEGF;
    for (int k = 0; k < NWARMF; ++k) {
        const int lid = j0 + k * 16;
        const float4 p = sref[lid];
        insertv(PACKQ(p, lid, qxA, qyA, qzA), bsA);
        insertv(PACKQ(p, lid, qxB, qyB, qzB), bsB);
        insertv(PACKQ(p, lid, qxC, qyC, qzC), bsC);
    }
    for (int c = 0; c < NCHF; ++c) {
        const int jj = j0 + c * 64;
        const float gA = GATE_OF(bsA[0]), gB = GATE_OF(bsB[0]), gC = GATE_OF(bsC[0]);
        unsigned mA0=0u,mA1=0u,mB0=0u,mB1=0u,mC0=0u,mC1=0u;
#pragma unroll
        for (int b = 0; b < 32; ++b) {
            const float4 p = sref[jj + b];
            mA0 |= (score4(p,qxA,qyA,qzA) > gA) ? (1u<<b) : 0u;
            mB0 |= (score4(p,qxB,qyB,qzB) > gB) ? (1u<<b) : 0u;
            mC0 |= (score4(p,qxC,qyC,qzC) > gC) ? (1u<<b) : 0u;
        }
#pragma unroll
        for (int b = 0; b < 32; ++b) {
            const float4 p = sref[jj + 32 + b];
            mA1 |= (score4(p,qxA,qyA,qzA) > gA) ? (1u<<b) : 0u;
            mB1 |= (score4(p,qxB,qyB,qzB) > gB) ? (1u<<b) : 0u;
            mC1 |= (score4(p,qxC,qyC,qzC) > gC) ? (1u<<b) : 0u;
        }
        mA0 &= ~0x00010001u; mA1 &= ~0x00010001u;
        mB0 &= ~0x00010001u; mB1 &= ~0x00010001u;
        mC0 &= ~0x00010001u; mC1 &= ~0x00010001u;
        while (__any((mA0|mA1) != 0u)) {
            if (mA0) { const int b=__builtin_ctz(mA0); mA0 &= mA0-1u;
                const int lid=jj+b;    insertv(PACKQ(sref[lid],lid,qxA,qyA,qzA), bsA); }
            if (mA1) { const int b=__builtin_ctz(mA1); mA1 &= mA1-1u;
                const int lid=jj+32+b; insertv(PACKQ(sref[lid],lid,qxA,qyA,qzA), bsA); }
        }
        while (__any((mB0|mB1) != 0u)) {
            if (mB0) { const int b=__builtin_ctz(mB0); mB0 &= mB0-1u;
                const int lid=jj+b;    insertv(PACKQ(sref[lid],lid,qxB,qyB,qzB), bsB); }
            if (mB1) { const int b=__builtin_ctz(mB1); mB1 &= mB1-1u;
                const int lid=jj+32+b; insertv(PACKQ(sref[lid],lid,qxB,qyB,qzB), bsB); }
        }
        while (__any((mC0|mC1) != 0u)) {
            if (mC0) { const int b=__builtin_ctz(mC0); mC0 &= mC0-1u;
                const int lid=jj+b;    insertv(PACKQ(sref[lid],lid,qxC,qyC,qzC), bsC); }
            if (mC1) { const int b=__builtin_ctz(mC1); mC1 &= mC1-1u;
                const int lid=jj+32+b; insertv(PACKQ(sref[lid],lid,qxC,qyC,qzC), bsC); }
        }
    }
    __syncthreads();
    if (seg >= 2) { const int slot = tid - 128;
#pragma unroll
        for (int i = 0; i < K_NN; ++i) {
            mbuf[(slot*QSL+0)*K_NN+i]=bsA[i]; mbuf[(slot*QSL+1)*K_NN+i]=bsB[i];
            mbuf[(slot*QSL+2)*K_NN+i]=bsC[i]; } }
    __syncthreads();
    if (seg < 2) { const int src = seg*64 + qlane;
#pragma unroll
        for (int i = 0; i < K_NN; ++i) {
            insertv(mbuf[(src*QSL+0)*K_NN+i], bsA); insertv(mbuf[(src*QSL+1)*K_NN+i], bsB);
            insertv(mbuf[(src*QSL+2)*K_NN+i], bsC); } }
    __syncthreads();
    if (seg == 1) {
#pragma unroll
        for (int i = 0; i < K_NN; ++i) {
            mbuf[(qlane*QSL+0)*K_NN+i]=bsA[i]; mbuf[(qlane*QSL+1)*K_NN+i]=bsB[i];
            mbuf[(qlane*QSL+2)*K_NN+i]=bsC[i]; } }
    __syncthreads();
    if (seg == 0) {
#pragma unroll
        for (int i = 0; i < K_NN; ++i) {
            insertv(mbuf[(qlane*QSL+0)*K_NN+i], bsA); insertv(mbuf[(qlane*QSL+1)*K_NN+i], bsB);
            insertv(mbuf[(qlane*QSL+2)*K_NN+i], bsC); }
        const float* nrm_base = points + (size_t)r * N_PTS * 6 + 3;
        { int votes=0; float s_best=-3.4e38f;
#pragma unroll
          for (int i = 0; i < K_NN; ++i) {
            const int id=(int)(__float_as_uint(bsA[i])&IDMASK); const float4 p=sref[id];
            const float s=score4(p,qxA,qyA,qzA); if (i==K_NN-1) s_best=s;
            const float* nb=nrm_base+(size_t)id*6;
            votes += (fmaf(nb[0],p.x-qxA,fmaf(nb[1],p.y-qyA,nb[2]*(p.z-qzA)))>0.0f)?1:0; }
          const float d0=sqrtf(fmaxf(fmaf(-2.0f,s_best,qqA),0.0f));
          pair_sd[((size_t)q*NSLOT+rs)*N_PTS+nqA]=(votes>8)?-d0:d0; }
        { int votes=0; float s_best=-3.4e38f;
#pragma unroll
          for (int i = 0; i < K_NN; ++i) {
            const int id=(int)(__float_as_uint(bsB[i])&IDMASK); const float4 p=sref[id];
            const float s=score4(p,qxB,qyB,qzB); if (i==K_NN-1) s_best=s;
            const float* nb=nrm_base+(size_t)id*6;
            votes += (fmaf(nb[0],p.x-qxB,fmaf(nb[1],p.y-qyB,nb[2]*(p.z-qzB)))>0.0f)?1:0; }
          const float d0=sqrtf(fmaxf(fmaf(-2.0f,s_best,qqB),0.0f));
          pair_sd[((size_t)q*NSLOT+rs)*N_PTS+nqB]=(votes>8)?-d0:d0; }
        { int votes=0; float s_best=-3.4e38f;
#pragma unroll
          for (int i = 0; i < K_NN; ++i) {
            const int id=(int)(__float_as_uint(bsC[i])&IDMASK); const float4 p=sref[id];
            const float s=score4(p,qxC,qyC,qzC); if (i==K_NN-1) s_best=s;
            const float* nb=nrm_base+(size_t)id*6;
            votes += (fmaf(nb[0],p.x-qxC,fmaf(nb[1],p.y-qyC,nb[2]*(p.z-qzC)))>0.0f)?1:0; }
          const float d0=sqrtf(fmaxf(fmaf(-2.0f,s_best,qqC),0.0f));
          pair_sd[((size_t)q*NSLOT+rs)*N_PTS+nqC]=(votes>8)?-d0:d0; }
    }
}

__global__ __launch_bounds__(256) void reduce_kernel_fb(
        const float* __restrict__ points, const float* __restrict__ estT,
        const float* __restrict__ planeT, const float* __restrict__ pair_sd,
        float* __restrict__ out) {
    int i = blockIdx.x * blockDim.x + threadIdx.x;
    if (i >= M_OBJ * N_PTS) return;
    int m = i / N_PTS, n = i % N_PTS;
    float T[3][4];
    make_T(estT + m * 16, planeT, T);
    const float* p = points + (size_t)i * 6;
    float sd = T[2][0]*p[0] + T[2][1]*p[1] + T[2][2]*p[2] + T[2][3];
#pragma unroll
    for (int rs = 0; rs < NSLOT; ++rs)
        sd = fminf(sd, pair_sd[((size_t)m * NSLOT + rs) * N_PTS + n]);
    out[i] = sd;
    out[M_OBJ * N_PTS + i] = (sd < -0.01f) ? 1.0f : 0.0f;
}

extern "C" void kernel_launch(void* const* d_in, const int* in_sizes, int n_in,
                              void* d_out, int out_size, void* d_ws, size_t ws_size,
                              hipStream_t stream) {
    const float* points = (const float*)d_in[0];
    const float* estT   = (const float*)d_in[1];
    const float* planeT = (const float*)d_in[2];
    const size_t need = (size_t)12 * HSPLIT * K_NN * N_PTS * sizeof(float); // 5.9 MB
    const int total = M_OBJ * N_PTS;

    if (ws_size >= need) {
        float* part = (float*)d_ws;
        dim3 grid(M_OBJ * NSLOT, NQCH, HSPLIT);     // 12 x 16 x 4 = 768 blocks
        pair_part_kernel<<<grid, 256, 0, stream>>>(points, estT, planeT, part);
        merge_kernel<<<(total + 255) / 256, 256, 0, stream>>>(points, estT, planeT,
                                                              part, (float*)d_out);
    } else {
        float* pair_sd = (float*)d_ws;
        dim3 gridB(M_OBJ * NSLOT, NQCH);            // 12 x 16
        pair_kernel_fb<<<gridB, 256, 0, stream>>>(points, estT, planeT, pair_sd);
        reduce_kernel_fb<<<(total + 255) / 256, 256, 0, stream>>>(points, estT, planeT,
                                                                  pair_sd, (float*)d_out);
    }
}

// Round 14
// 123.821 us; speedup vs baseline: 1.6459x; 1.6459x over previous
//
#include <hip/hip_runtime.h>
#include <math.h>

#define M_OBJ 4
#define N_PTS 3072
#define K_NN  10
#define NSLOT (M_OBJ - 1)
#define QPB   64            // queries per block (one per lane, Q=1)
#define SEGN  (N_PTS / 4)   // 768 points per wave segment
#define NCHUNK (SEGN / 64)  // 12
#define NWARM (SEGN / 16)   // 48 warm points, stride 16
#define IDMASK 0xFFFu

// T = inv(plane_T) @ est_T (3x4). plane_T orthonormal-rigid: inv = [R^T|-R^T t].
__device__ inline void make_T(const float* __restrict__ E,
                              const float* __restrict__ P,
                              float T[3][4]) {
    float Pi[3][4];
#pragma unroll
    for (int i = 0; i < 3; ++i) {
#pragma unroll
        for (int j = 0; j < 3; ++j) Pi[i][j] = P[j * 4 + i];
        Pi[i][3] = -(P[0 * 4 + i] * P[3] + P[1 * 4 + i] * P[7] + P[2 * 4 + i] * P[11]);
    }
#pragma unroll
    for (int i = 0; i < 3; ++i) {
#pragma unroll
        for (int j = 0; j < 4; ++j) {
            float acc = (j == 3) ? Pi[i][3] : 0.0f;
#pragma unroll
            for (int kk = 0; kk < 3; ++kk) acc += Pi[i][kk] * E[kk * 4 + j];
            T[i][j] = acc;
        }
    }
}

// ascending insert-drop-min via med3 identity; no-op when v <= bs[0]
__device__ __forceinline__ void insertv(float v, float bs[K_NN]) {
#pragma unroll
    for (int i = 0; i < K_NN - 1; ++i)
        bs[i] = __builtin_amdgcn_fmed3f(v, bs[i], bs[i + 1]);
    bs[K_NN - 1] = fmaxf(v, bs[K_NN - 1]);
}

__device__ __forceinline__ float score4(const float4 p, float qx, float qy, float qz) {
    return fmaf(p.x, qx, fmaf(p.y, qy, fmaf(p.z, qz, -p.w)));
}

#define PACKQ(P, LID, QX, QY, QZ) \
    __uint_as_float((__float_as_uint(score4((P), (QX), (QY), (QZ))) & ~IDMASK) | (unsigned)(LID))
// slack 1e-3 relative covers the 12-bit id packing (~4.9e-4 rel) conservatively
#define GATE_OF(B0) (fmaf(-fabsf(B0), 1.0e-3f, (B0)) - 1e-30f)

__global__ __launch_bounds__(256, 3) void pair_kernel(
        const float* __restrict__ points,   // [M][N][6]
        const float* __restrict__ estT,     // [M][4][4]
        const float* __restrict__ planeT,   // [4][4]
        float* __restrict__ pair_sd) {      // [M][NSLOT][N]
    __shared__ float4 sref[N_PTS];          // 49152 B: (x,y,z,|p|^2/2)
    __shared__ float  mbuf[128 * K_NN];     // 5120 B: thr exchange + merge

    const int pidx  = blockIdx.x;           // 0..11
    const int q     = pidx / NSLOT;
    const int rs    = pidx % NSLOT;
    const int r     = rs + (rs >= q ? 1 : 0);
    const int tid   = threadIdx.x;
    const int seg   = tid >> 6;
    const int qlane = tid & 63;

    float Tq[3][4], Tr[3][4];
    make_T(estT + q * 16, planeT, Tq);
    make_T(estT + r * 16, planeT, Tr);

    for (int j = tid; j < N_PTS; j += 256) {
        const float* p = points + (size_t)(r * N_PTS + j) * 6;
        float2 xy = *(const float2*)p;
        float  z  = p[2];
        float px = Tr[0][0] * xy.x + Tr[0][1] * xy.y + Tr[0][2] * z + Tr[0][3];
        float py = Tr[1][0] * xy.x + Tr[1][1] * xy.y + Tr[1][2] * z + Tr[1][3];
        float pz = Tr[2][0] * xy.x + Tr[2][1] * xy.y + Tr[2][2] * z + Tr[2][3];
        sref[j] = make_float4(px, py, pz, 0.5f * (px * px + py * py + pz * pz));
    }
    __syncthreads();

    const int nq = blockIdx.y * QPB + qlane;
    const float* qp = points + (size_t)(q * N_PTS + nq) * 6;
    float2 qxy = *(const float2*)qp;
    float  qzz = qp[2];
    const float qx = Tq[0][0]*qxy.x + Tq[0][1]*qxy.y + Tq[0][2]*qzz + Tq[0][3];
    const float qy = Tq[1][0]*qxy.x + Tq[1][1]*qxy.y + Tq[1][2]*qzz + Tq[1][3];
    const float qz = Tq[2][0]*qxy.x + Tq[2][1]*qxy.y + Tq[2][2]*qzz + Tq[2][3];
    const float qq = qx*qx + qy*qy + qz*qz;   // sq = qq - 2s

    float bs[K_NN];
#pragma unroll
    for (int i = 0; i < K_NN; ++i) bs[i] = -3.4e38f;

    const int j0 = seg * SEGN;

    // warm start: 48 strided points per wave segment
#pragma unroll 4
    for (int t = 0; t < NWARM; ++t) {
        const int lid = j0 + t * 16;
        insertv(PACKQ(sref[lid], lid, qx, qy, qz), bs);
    }

    // cross-wave threshold share: 4x48 = 192-sample gate. A partial 10th-best
    // is always <= the final 10th-best, so max over waves is a valid
    // conservative gate (with GATE_OF slack for packing/ties).
    mbuf[seg * 64 + qlane] = bs[0];
    __syncthreads();
    float sthr = fmaxf(fmaxf(mbuf[qlane], mbuf[64 + qlane]),
                       fmaxf(mbuf[128 + qlane], mbuf[192 + qlane]));

    // 6 double-chunks of 128 points. Scan: branch-free mask build into 4
    // registers; walk: 4 independent chains -> 4 LDS reloads in flight.
    for (int c = 0; c < NCHUNK; c += 2) {
        if (c == 6) {                        // mid-scan gate re-tighten
            __syncthreads();                 // all waves past previous reads
            mbuf[seg * 64 + qlane] = bs[0];
            __syncthreads();
            sthr = fmaxf(fmaxf(mbuf[qlane], mbuf[64 + qlane]),
                         fmaxf(mbuf[128 + qlane], mbuf[192 + qlane]));
        }
        const int jj = j0 + c * 64;
        const float g = GATE_OF(fmaxf(bs[0], sthr));
        unsigned u0 = 0u, u1 = 0u, v0 = 0u, v1 = 0u;
#pragma unroll
        for (int b = 0; b < 32; ++b) {
            float s = score4(sref[jj + b], qx, qy, qz);
            u0 |= (s > g) ? (1u << b) : 0u;
        }
#pragma unroll
        for (int b = 0; b < 32; ++b) {
            float s = score4(sref[jj + 32 + b], qx, qy, qz);
            u1 |= (s > g) ? (1u << b) : 0u;
        }
#pragma unroll
        for (int b = 0; b < 32; ++b) {
            float s = score4(sref[jj + 64 + b], qx, qy, qz);
            v0 |= (s > g) ? (1u << b) : 0u;
        }
#pragma unroll
        for (int b = 0; b < 32; ++b) {
            float s = score4(sref[jj + 96 + b], qx, qy, qz);
            v1 |= (s > g) ? (1u << b) : 0u;
        }
        // warm points (bit 0,16 of each half-chunk) already inserted
        u0 &= ~0x00010001u; u1 &= ~0x00010001u;
        v0 &= ~0x00010001u; v1 &= ~0x00010001u;

        while (__any((u0 | u1 | v0 | v1) != 0u)) {
            if (u0) { const int b = __builtin_ctz(u0); u0 &= u0 - 1u;
                const int lid = jj + b;      insertv(PACKQ(sref[lid], lid, qx, qy, qz), bs); }
            if (u1) { const int b = __builtin_ctz(u1); u1 &= u1 - 1u;
                const int lid = jj + 32 + b; insertv(PACKQ(sref[lid], lid, qx, qy, qz), bs); }
            if (v0) { const int b = __builtin_ctz(v0); v0 &= v0 - 1u;
                const int lid = jj + 64 + b; insertv(PACKQ(sref[lid], lid, qx, qy, qz), bs); }
            if (v1) { const int b = __builtin_ctz(v1); v1 &= v1 - 1u;
                const int lid = jj + 96 + b; insertv(PACKQ(sref[lid], lid, qx, qy, qz), bs); }
        }
    }

    // cascade merge (ids in low bits; segments disjoint -> no dupes)
    __syncthreads();
    if (seg >= 2) {
        const int slot = tid - 128;
#pragma unroll
        for (int i = 0; i < K_NN; ++i) mbuf[slot * K_NN + i] = bs[i];
    }
    __syncthreads();
    if (seg < 2) {
        const int src = (seg * 64 + qlane) * K_NN;
#pragma unroll
        for (int i = 0; i < K_NN; ++i) insertv(mbuf[src + i], bs);
    }
    __syncthreads();
    if (seg == 1) {
#pragma unroll
        for (int i = 0; i < K_NN; ++i) mbuf[qlane * K_NN + i] = bs[i];
    }
    __syncthreads();
    if (seg == 0) {
        const int src = qlane * K_NN;
#pragma unroll
        for (int i = 0; i < K_NN; ++i) insertv(mbuf[src + i], bs);

        // result-frequency finalize: 10 ids -> votes + exact nearest dist
        const float* nrm_base = points + (size_t)r * N_PTS * 6 + 3;
        int votes = 0;
        float s_best = -3.4e38f;
#pragma unroll
        for (int i = 0; i < K_NN; ++i) {
            const int id = (int)(__float_as_uint(bs[i]) & IDMASK);
            const float4 p = sref[id];
            const float s = score4(p, qx, qy, qz);
            if (i == K_NN - 1) s_best = s;      // bs[9] = nearest
            const float* nb = nrm_base + (size_t)id * 6;
            votes += (fmaf(nb[0], p.x-qx, fmaf(nb[1], p.y-qy, nb[2]*(p.z-qz))) > 0.0f) ? 1 : 0;
        }

        const float d0 = sqrtf(fmaxf(fmaf(-2.0f, s_best, qq), 0.0f));
        pair_sd[((size_t)q * NSLOT + rs) * N_PTS + nq] = (votes > 8) ? -d0 : d0;
    }
}

__global__ __launch_bounds__(256) void reduce_kernel(
        const float* __restrict__ points,
        const float* __restrict__ estT,
        const float* __restrict__ planeT,
        const float* __restrict__ pair_sd,
        float* __restrict__ out) {
    int i = blockIdx.x * blockDim.x + threadIdx.x;
    if (i >= M_OBJ * N_PTS) return;
    int m = i / N_PTS, n = i % N_PTS;

    float T[3][4];
    make_T(estT + m * 16, planeT, T);
    const float* p = points + (size_t)i * 6;
    float sd = T[2][0]*p[0] + T[2][1]*p[1] + T[2][2]*p[2] + T[2][3];
#pragma unroll
    for (int rs = 0; rs < NSLOT; ++rs)
        sd = fminf(sd, pair_sd[((size_t)m * NSLOT + rs) * N_PTS + n]);

    out[i] = sd;
    out[M_OBJ * N_PTS + i] = (sd < -0.01f) ? 1.0f : 0.0f;
}

extern "C" void kernel_launch(void* const* d_in, const int* in_sizes, int n_in,
                              void* d_out, int out_size, void* d_ws, size_t ws_size,
                              hipStream_t stream) {
    const float* points = (const float*)d_in[0];   // [4][3072][6]
    const float* estT   = (const float*)d_in[1];   // [4][4][4]
    const float* planeT = (const float*)d_in[2];   // [4][4]

    float* pair_sd = (float*)d_ws;                 // [4][3][3072] = 147 KB

    dim3 gridB(M_OBJ * NSLOT, N_PTS / QPB);        // 12 x 48 = 576 blocks
    pair_kernel<<<gridB, 256, 0, stream>>>(points, estT, planeT, pair_sd);

    int total = M_OBJ * N_PTS;
    reduce_kernel<<<(total + 255) / 256, 256, 0, stream>>>(points, estT, planeT,
                                                           pair_sd, (float*)d_out);
}